// Round 1
// baseline (657.849 us; speedup 1.0000x reference)
//
#include <hip/hip_runtime.h>

#define L_LEN 131072
#define NB    2048

typedef unsigned short u16;
typedef __attribute__((ext_vector_type(4))) float f32x4;
typedef __attribute__((ext_vector_type(8))) short s16x8;
typedef __attribute__((ext_vector_type(4))) short s16x4;

// ---- workspace byte offsets ----
#define WS_OUTB  0ull            // u16[256*131072]        = 67108864 B
#define WS_PSUM  67108864ull     // float[256*2048]        = 2097152 B
#define WS_PSQ   69206016ull     // float[256*2048]
#define WS_MEAN  71303168ull     // float[256]
#define WS_RSTD  71304192ull     // float[256]
#define WS_WFFB  71305216ull     // short[256*768]  (k = t*256+c)
#define WS_WQB   71698432ull     // short[128*256]
#define WS_WKB   71763968ull
#define WS_WVB   71829504ull
#define WS_WOB   71895040ull     // short[256*128]
#define WS_WCB   71960576ull     // short[256*256]

#define SMEM_BYTES 124416

__device__ __forceinline__ u16 f2bf(float v){
  union { float f; unsigned u; } a; a.f = v;
  unsigned r = a.u + 0x7fffu + ((a.u >> 16) & 1u);
  return (u16)(r >> 16);
}
__device__ __forceinline__ float bf2f(u16 u){
  union { unsigned u; float f; } a; a.u = ((unsigned)u) << 16; return a.f;
}
__device__ __forceinline__ f32x4 mfma16(s16x8 a, s16x8 b, f32x4 c){
  return __builtin_amdgcn_mfma_f32_16x16x32_bf16(a, b, c, 0, 0, 0);
}
__device__ __forceinline__ s16x8 ld8(const void* p){ return *(const s16x8*)p; }

// ---------------- K0: weight prep (fp32 -> bf16; Wff transposed) ----------------
__global__ __launch_bounds__(256) void k_prep(
    const float* __restrict__ Wff, const float* __restrict__ Wq,
    const float* __restrict__ Wk,  const float* __restrict__ Wv,
    const float* __restrict__ Wo,  const float* __restrict__ Wc,
    short* __restrict__ wffb, short* __restrict__ wqb, short* __restrict__ wkb,
    short* __restrict__ wvb,  short* __restrict__ wob, short* __restrict__ wcb)
{
  int i = blockIdx.x * 256 + threadIdx.x;
  if (i < 196608){
    int o = i / 768, kk = i % 768;
    int t = kk >> 8, c = kk & 255;
    wffb[i] = (short)f2bf(Wff[(o*256 + c)*3 + t]);
  } else if (i < 229376){ int j = i - 196608; wqb[j] = (short)f2bf(Wq[j]); }
  else if (i < 262144){ int j = i - 229376; wkb[j] = (short)f2bf(Wk[j]); }
  else if (i < 294912){ int j = i - 262144; wvb[j] = (short)f2bf(Wv[j]); }
  else if (i < 327680){ int j = i - 294912; wob[j] = (short)f2bf(Wo[j]); }
  else if (i < 393216){ int j = i - 327680; wcb[j] = (short)f2bf(Wc[j]); }
}

// ---------------- K1: dilated conv as GEMM (out = relu(Wcat @ X3 + bff)) ----------------
// out tile: 256 ch x 64 pos per WG. K = 768 (k = t*256 + c). Also emits per-WG stats.
__global__ __launch_bounds__(256) void k_conv(
    const float* __restrict__ x, const short* __restrict__ wffb,
    const float* __restrict__ bff, u16* __restrict__ outb,
    float* __restrict__ psum, float* __restrict__ psq)
{
  __shared__ u16 blds[64][40];   // [pos][c_local(32)+pad8], row stride 80B (16B-aligned)
  const int wg = blockIdx.x, l0 = wg * 64;
  const int tid = threadIdx.x;
  const int w = tid >> 6, lane = tid & 63, p = lane & 15, g = lane >> 4;
  f32x4 acc[4][4] = {};
  #pragma unroll 1
  for (int ks = 0; ks < 24; ++ks){
    const int t = ks >> 3, c0 = (ks & 7) * 32;
    { // stage B: x[c0+cl][l0 + 64*(t-1) + pos], zero-padded (range is fully in or fully out)
      const int cl = tid & 31, pg = tid >> 5;
      const long srcbase = (long)l0 + 64*(t-1);
      float vv[8];
      if (srcbase >= 0 && srcbase < L_LEN){
        const f32x4* sp = (const f32x4*)(x + (size_t)(c0+cl)*L_LEN + srcbase + pg*8);
        f32x4 a0 = sp[0], a1 = sp[1];
        vv[0]=a0[0];vv[1]=a0[1];vv[2]=a0[2];vv[3]=a0[3];
        vv[4]=a1[0];vv[5]=a1[1];vv[6]=a1[2];vv[7]=a1[3];
      } else {
        #pragma unroll
        for (int u = 0; u < 8; ++u) vv[u] = 0.f;
      }
      #pragma unroll
      for (int u = 0; u < 8; ++u) blds[pg*8 + u][cl] = f2bf(vv[u]);
    }
    __syncthreads();
    s16x8 af[4];
    #pragma unroll
    for (int fm = 0; fm < 4; ++fm)
      af[fm] = ld8(wffb + (size_t)(64*w + 16*fm + p)*768 + ks*32 + 8*g);
    #pragma unroll
    for (int fn = 0; fn < 4; ++fn){
      s16x8 b = ld8(&blds[16*fn + p][8*g]);
      #pragma unroll
      for (int fm = 0; fm < 4; ++fm)
        acc[fm][fn] = mfma16(af[fm], b, acc[fm][fn]);
    }
    __syncthreads();
  }
  // epilogue: bias + relu + store bf16 + per-row stats (deterministic)
  #pragma unroll
  for (int fm = 0; fm < 4; ++fm){
    #pragma unroll
    for (int i = 0; i < 4; ++i){
      const int o = 64*w + 16*fm + 4*g + i;
      const float bias = bff[o];
      float ssum = 0.f, ssq = 0.f;
      #pragma unroll
      for (int fn = 0; fn < 4; ++fn){
        float val = fmaxf(acc[fm][fn][i] + bias, 0.f);
        outb[(size_t)o*L_LEN + l0 + 16*fn + p] = f2bf(val);
        ssum += val; ssq += val*val;
      }
      #pragma unroll
      for (int d = 1; d < 16; d <<= 1){
        ssum += __shfl_xor(ssum, d, 16);
        ssq  += __shfl_xor(ssq,  d, 16);
      }
      if (p == 0){
        psum[(size_t)o*NB + wg] = ssum;
        psq [(size_t)o*NB + wg] = ssq;
      }
    }
  }
}

// ---------------- K2: finalize instance-norm stats ----------------
__global__ __launch_bounds__(256) void k_stats(
    const float* __restrict__ psum, const float* __restrict__ psq,
    float* __restrict__ mean, float* __restrict__ rstd)
{
  __shared__ float ss[256], sq[256];
  const int ch = blockIdx.x, tid = threadIdx.x;
  float a = 0.f, b = 0.f;
  for (int j = tid; j < NB; j += 256){ a += psum[(size_t)ch*NB + j]; b += psq[(size_t)ch*NB + j]; }
  ss[tid] = a; sq[tid] = b;
  __syncthreads();
  for (int st = 128; st > 0; st >>= 1){
    if (tid < st){ ss[tid] += ss[tid+st]; sq[tid] += sq[tid+st]; }
    __syncthreads();
  }
  if (tid == 0){
    float m = ss[0] / (float)L_LEN;
    float v = sq[0] / (float)L_LEN - m*m;
    mean[ch] = m;
    rstd[ch] = rsqrtf(v + 1e-5f);
  }
}

// ---------------- K3: fused norm->qkv->attention->Wo->Wc per 64-pos block ----------------
__global__ __launch_bounds__(256) void k_fused(
    const float* __restrict__ x, const float* __restrict__ fin,
    const float* __restrict__ mask,
    const float* __restrict__ bq, const float* __restrict__ bk,
    const float* __restrict__ bv, const float* __restrict__ bo,
    const float* __restrict__ bc,
    const u16* __restrict__ outb,
    const short* __restrict__ wqb, const short* __restrict__ wkb,
    const short* __restrict__ wvb, const short* __restrict__ wob,
    const short* __restrict__ wcb,
    const float* __restrict__ meanG, const float* __restrict__ rstdG,
    float* __restrict__ dout)
{
  extern __shared__ char smem[];
  u16* xnb    = (u16*)(smem);            // [128 pos][136]  staging (f, then xn)
  u16* hlds   = (u16*)(smem);            // [64 l][264]     overlays xnb (xn dead by then)
  u16* klds   = (u16*)(smem + 34816);    // [128 m][136]
  u16* plds   = (u16*)(smem + 34816);    // [64 l][136]     overlays klds after energy
  u16* rovlds = (u16*)(smem + 52224);    // [64 l][136]
  u16* vlds   = (u16*)(smem + 69632);    // [128 cv][136]
  u16* qlds   = (u16*)(smem + 104448);   // [64 l][136]
  float* meanS = (float*)(smem + 121856);
  float* rstdS = (float*)(smem + 122880);
  float* maskw = (float*)(smem + 123904); // [128]

  const int tid = threadIdx.x;
  const int w = tid >> 6, lane = tid & 63, p = lane & 15, g = lane >> 4;
  const int n = blockIdx.x, s = n * 64;
  const float SCALE = 0.08838834764831845f;  // 1/sqrt(128)

  meanS[tid] = meanG[tid]; rstdS[tid] = rstdG[tid];
  if (tid < 128){ int wp = s - 32 + tid; maskw[tid] = (wp >= 0 && wp < L_LEN) ? mask[wp] : 0.f; }
  __syncthreads();

  auto stageF = [&](int hc){
    #pragma unroll
    for (int rep = 0; rep < 8; ++rep){
      const int cl = rep*16 + (tid >> 4);
      const int pos0 = (tid & 15) * 8;
      const int wp0 = s - 32 + pos0;
      const float* src = fin + (size_t)(128*hc + cl)*L_LEN;
      float vv[8];
      if (wp0 >= 0 && wp0 + 8 <= L_LEN){
        const f32x4* sp = (const f32x4*)(src + wp0);
        f32x4 a0 = sp[0], a1 = sp[1];
        vv[0]=a0[0];vv[1]=a0[1];vv[2]=a0[2];vv[3]=a0[3];
        vv[4]=a1[0];vv[5]=a1[1];vv[6]=a1[2];vv[7]=a1[3];
      } else {
        #pragma unroll
        for (int u = 0; u < 8; ++u){
          int wp = wp0 + u;
          vv[u] = (wp >= 0 && wp < L_LEN) ? src[wp] : 0.f;
        }
      }
      #pragma unroll
      for (int u = 0; u < 8; ++u) xnb[(pos0 + u)*136 + cl] = f2bf(vv[u]);
    }
  };
  auto stageXN = [&](int hc){
    #pragma unroll
    for (int rep = 0; rep < 8; ++rep){
      const int cl = rep*16 + (tid >> 4);
      const int ch = 128*hc + cl;
      const float mu = meanS[ch], rs = rstdS[ch];
      const u16* src = outb + (size_t)ch*L_LEN;
      const int pos0 = (tid & 15) * 8;
      const int wp0 = s - 32 + pos0;
      float vv[8];
      if (wp0 >= 0 && wp0 + 8 <= L_LEN){
        s16x8 uv = *(const s16x8*)(src + wp0);
        #pragma unroll
        for (int u = 0; u < 8; ++u) vv[u] = (bf2f((u16)uv[u]) - mu) * rs;
      } else {
        #pragma unroll
        for (int u = 0; u < 8; ++u){
          int wp = wp0 + u;
          vv[u] = (wp >= 0 && wp < L_LEN) ? (bf2f(src[wp]) - mu) * rs : 0.f;
        }
      }
      #pragma unroll
      for (int u = 0; u < 8; ++u) xnb[(pos0 + u)*136 + cl] = f2bf(vv[u]);
    }
  };

  // ---------- Phase 1: v = Wv @ f_window + bv (K split in 2 halves) ----------
  f32x4 accv[2][8] = {};
  #pragma unroll 1
  for (int hc = 0; hc < 2; ++hc){
    stageF(hc);
    __syncthreads();
    #pragma unroll
    for (int kk = 0; kk < 4; ++kk){
      s16x8 a0 = ld8(wvb + (size_t)(32*w +      p)*256 + 128*hc + 32*kk + 8*g);
      s16x8 a1 = ld8(wvb + (size_t)(32*w + 16 + p)*256 + 128*hc + 32*kk + 8*g);
      #pragma unroll
      for (int fn = 0; fn < 8; ++fn){
        s16x8 b = ld8(&xnb[(16*fn + p)*136 + 32*kk + 8*g]);
        accv[0][fn] = mfma16(a0, b, accv[0][fn]);
        accv[1][fn] = mfma16(a1, b, accv[1][fn]);
      }
    }
    __syncthreads();
  }
  // v epilogue: +bv, zero at padded window positions, scatter to vlds[cv][m]
  #pragma unroll
  for (int fm = 0; fm < 2; ++fm){
    #pragma unroll
    for (int fn = 0; fn < 8; ++fn){
      const int mm = 16*fn + p;
      const int wp = s - 32 + mm;
      const bool ok = (wp >= 0 && wp < L_LEN);
      #pragma unroll
      for (int i = 0; i < 4; ++i){
        const int cv = 32*w + 16*fm + 4*g + i;
        float val = ok ? (accv[fm][fn][i] + bv[cv]) : 0.f;
        vlds[cv*136 + mm] = f2bf(val);
      }
    }
  }

  // ---------- Phase 2: q = Wq@xn (center), k = Wk@xn (window) ----------
  f32x4 accq[2][4] = {};
  f32x4 acck[2][8] = {};
  #pragma unroll 1
  for (int hc = 0; hc < 2; ++hc){
    stageXN(hc);
    __syncthreads();
    #pragma unroll
    for (int kk = 0; kk < 4; ++kk){
      s16x8 aq0 = ld8(wqb + (size_t)(32*w +      p)*256 + 128*hc + 32*kk + 8*g);
      s16x8 aq1 = ld8(wqb + (size_t)(32*w + 16 + p)*256 + 128*hc + 32*kk + 8*g);
      s16x8 ak0 = ld8(wkb + (size_t)(32*w +      p)*256 + 128*hc + 32*kk + 8*g);
      s16x8 ak1 = ld8(wkb + (size_t)(32*w + 16 + p)*256 + 128*hc + 32*kk + 8*g);
      #pragma unroll
      for (int fn = 0; fn < 8; ++fn){
        s16x8 b = ld8(&xnb[(16*fn + p)*136 + 32*kk + 8*g]);
        acck[0][fn] = mfma16(ak0, b, acck[0][fn]);
        acck[1][fn] = mfma16(ak1, b, acck[1][fn]);
        if (fn >= 2 && fn < 6){  // center cols: window m = l + 32
          accq[0][fn-2] = mfma16(aq0, b, accq[0][fn-2]);
          accq[1][fn-2] = mfma16(aq1, b, accq[1][fn-2]);
        }
      }
    }
    __syncthreads();
  }
  // q epilogue -> qlds[l][qc] (packed b64)
  #pragma unroll
  for (int fm = 0; fm < 2; ++fm){
    #pragma unroll
    for (int fn = 0; fn < 4; ++fn){
      const int l_ = 16*fn + p;
      s16x4 pk;
      #pragma unroll
      for (int i = 0; i < 4; ++i){
        const int qc = 32*w + 16*fm + 4*g + i;
        pk[i] = (short)f2bf(accq[fm][fn][i] + bq[qc]);
      }
      *(s16x4*)(&qlds[l_*136 + 32*w + 16*fm + 4*g]) = pk;
    }
  }
  // k epilogue -> klds[m][kc], zero at padded positions
  #pragma unroll
  for (int fm = 0; fm < 2; ++fm){
    #pragma unroll
    for (int fn = 0; fn < 8; ++fn){
      const int mm = 16*fn + p;
      const int wp = s - 32 + mm;
      const bool ok = (wp >= 0 && wp < L_LEN);
      s16x4 pk;
      #pragma unroll
      for (int i = 0; i < 4; ++i){
        const int kc = 32*w + 16*fm + 4*g + i;
        pk[i] = ok ? (short)f2bf(acck[fm][fn][i] + bk[kc]) : (short)0;
      }
      *(s16x4*)(&klds[mm*136 + 32*w + 16*fm + 4*g]) = pk;
    }
  }
  __syncthreads();

  // ---------- Phase 3: energy + softmax ----------
  f32x4 e[8] = {};
  #pragma unroll
  for (int kk = 0; kk < 4; ++kk){
    s16x8 a = ld8(&qlds[(16*w + p)*136 + 32*kk + 8*g]);
    #pragma unroll
    for (int fn = 0; fn < 8; ++fn){
      s16x8 b = ld8(&klds[(16*fn + p)*136 + 32*kk + 8*g]);
      e[fn] = mfma16(a, b, e[fn]);
    }
  }
  float zb[8][4];
  float M[4] = {-1e30f, -1e30f, -1e30f, -1e30f};
  float S[4] = {0.f, 0.f, 0.f, 0.f};
  #pragma unroll
  for (int fn = 0; fn < 8; ++fn){
    #pragma unroll
    for (int i = 0; i < 4; ++i){
      const int mm = 16*fn + p;
      const int l_ = 16*w + 4*g + i;
      const int d = mm - l_;
      const float fmv = (d >= 0 && d < 64) ? maskw[mm] : 0.f;
      const float z = e[fn][i]*SCALE + logf(fmv + 1e-6f);
      zb[fn][i] = z;
      M[i] = fmaxf(M[i], z);
    }
  }
  #pragma unroll
  for (int i = 0; i < 4; ++i){
    #pragma unroll
    for (int d = 1; d < 16; d <<= 1) M[i] = fmaxf(M[i], __shfl_xor(M[i], d, 16));
  }
  #pragma unroll
  for (int fn = 0; fn < 8; ++fn){
    #pragma unroll
    for (int i = 0; i < 4; ++i){
      const float pv = expf(zb[fn][i] - M[i]);
      zb[fn][i] = pv;
      S[i] += pv;
    }
  }
  #pragma unroll
  for (int i = 0; i < 4; ++i){
    #pragma unroll
    for (int d = 1; d < 16; d <<= 1) S[i] += __shfl_xor(S[i], d, 16);
  }
  __syncthreads();  // all waves done reading klds before plds overlays it
  #pragma unroll
  for (int fn = 0; fn < 8; ++fn){
    #pragma unroll
    for (int i = 0; i < 4; ++i){
      const int mm = 16*fn + p;
      const int l_ = 16*w + 4*g + i;
      const int d = mm - l_;
      const float fmv = (d >= 0 && d < 64) ? maskw[mm] : 0.f;
      const float att = zb[fn][i] / S[i] * fmv;
      plds[l_*136 + mm] = f2bf(att);
    }
  }
  __syncthreads();

  // ---------- Phase 4: ov = v @ att^T, relu -> rovlds[l][cv] ----------
  f32x4 accp[2][4] = {};
  #pragma unroll
  for (int kk = 0; kk < 4; ++kk){
    s16x8 a0 = ld8(&vlds[(32*w +      p)*136 + 32*kk + 8*g]);
    s16x8 a1 = ld8(&vlds[(32*w + 16 + p)*136 + 32*kk + 8*g]);
    #pragma unroll
    for (int fn = 0; fn < 4; ++fn){
      s16x8 b = ld8(&plds[(16*fn + p)*136 + 32*kk + 8*g]);
      accp[0][fn] = mfma16(a0, b, accp[0][fn]);
      accp[1][fn] = mfma16(a1, b, accp[1][fn]);
    }
  }
  #pragma unroll
  for (int fm = 0; fm < 2; ++fm){
    #pragma unroll
    for (int fn = 0; fn < 4; ++fn){
      const int l_ = 16*fn + p;
      s16x4 pk;
      #pragma unroll
      for (int i = 0; i < 4; ++i)
        pk[i] = (short)f2bf(fmaxf(accp[fm][fn][i], 0.f));
      *(s16x4*)(&rovlds[l_*136 + 32*w + 16*fm + 4*g]) = pk;
    }
  }
  __syncthreads();

  // ---------- Phase 5: oo = Wo @ rov + bo; h = oo*pm + out -> hlds[l][o] ----------
  f32x4 acco[4][4] = {};
  #pragma unroll
  for (int kk = 0; kk < 4; ++kk){
    s16x8 a[4];
    #pragma unroll
    for (int fm = 0; fm < 4; ++fm)
      a[fm] = ld8(wob + (size_t)(64*w + 16*fm + p)*128 + 32*kk + 8*g);
    #pragma unroll
    for (int fn = 0; fn < 4; ++fn){
      s16x8 b = ld8(&rovlds[(16*fn + p)*136 + 32*kk + 8*g]);
      #pragma unroll
      for (int fm = 0; fm < 4; ++fm)
        acco[fm][fn] = mfma16(a[fm], b, acco[fm][fn]);
    }
  }
  #pragma unroll
  for (int fm = 0; fm < 4; ++fm){
    #pragma unroll
    for (int fn = 0; fn < 4; ++fn){
      const int l_ = 16*fn + p;
      const float pml = maskw[32 + l_];
      s16x4 pk;
      #pragma unroll
      for (int i = 0; i < 4; ++i){
        const int o = 64*w + 16*fm + 4*g + i;
        float hv = (acco[fm][fn][i] + bo[o]) * pml + bf2f(outb[(size_t)o*L_LEN + s + l_]);
        pk[i] = (short)f2bf(hv);
      }
      *(s16x4*)(&hlds[l_*264 + 64*w + 16*fm + 4*g]) = pk;
    }
  }
  __syncthreads();

  // ---------- Phase 6: y = Wc @ h + bc; out = (x + y) * mask ----------
  f32x4 accy[4][4] = {};
  #pragma unroll
  for (int kk = 0; kk < 8; ++kk){
    s16x8 a[4];
    #pragma unroll
    for (int fm = 0; fm < 4; ++fm)
      a[fm] = ld8(wcb + (size_t)(64*w + 16*fm + p)*256 + 32*kk + 8*g);
    #pragma unroll
    for (int fn = 0; fn < 4; ++fn){
      s16x8 b = ld8(&hlds[(16*fn + p)*264 + 32*kk + 8*g]);
      #pragma unroll
      for (int fm = 0; fm < 4; ++fm)
        accy[fm][fn] = mfma16(a[fm], b, accy[fm][fn]);
    }
  }
  #pragma unroll
  for (int fm = 0; fm < 4; ++fm){
    #pragma unroll
    for (int fn = 0; fn < 4; ++fn){
      const int l_ = 16*fn + p;
      const float ml = maskw[32 + l_];
      #pragma unroll
      for (int i = 0; i < 4; ++i){
        const int o = 64*w + 16*fm + 4*g + i;
        const size_t idx = (size_t)o*L_LEN + s + l_;
        dout[idx] = (x[idx] + accy[fm][fn][i] + bc[o]) * ml;
      }
    }
  }
}

extern "C" void kernel_launch(void* const* d_in, const int* in_sizes, int n_in,
                              void* d_out, int out_size, void* d_ws, size_t ws_size,
                              hipStream_t stream)
{
  (void)in_sizes; (void)n_in; (void)out_size; (void)ws_size;
  const float* x    = (const float*)d_in[0];
  const float* f    = (const float*)d_in[1];
  const float* mask = (const float*)d_in[2];
  const float* Wff  = (const float*)d_in[3];
  const float* bff  = (const float*)d_in[4];
  const float* Wq   = (const float*)d_in[5];
  const float* bq   = (const float*)d_in[6];
  const float* Wk   = (const float*)d_in[7];
  const float* bk   = (const float*)d_in[8];
  const float* Wv   = (const float*)d_in[9];
  const float* bv   = (const float*)d_in[10];
  const float* Wo   = (const float*)d_in[11];
  const float* bo   = (const float*)d_in[12];
  const float* Wc   = (const float*)d_in[13];
  const float* bc   = (const float*)d_in[14];

  char* ws = (char*)d_ws;
  u16*   outb = (u16*)(ws + WS_OUTB);
  float* psum = (float*)(ws + WS_PSUM);
  float* psq  = (float*)(ws + WS_PSQ);
  float* mean = (float*)(ws + WS_MEAN);
  float* rstd = (float*)(ws + WS_RSTD);
  short* wffb = (short*)(ws + WS_WFFB);
  short* wqb  = (short*)(ws + WS_WQB);
  short* wkb  = (short*)(ws + WS_WKB);
  short* wvb  = (short*)(ws + WS_WVB);
  short* wob  = (short*)(ws + WS_WOB);
  short* wcb  = (short*)(ws + WS_WCB);

  (void)hipFuncSetAttribute((const void*)k_fused,
                            hipFuncAttributeMaxDynamicSharedMemorySize, SMEM_BYTES);

  k_prep <<<1536, 256, 0, stream>>>(Wff, Wq, Wk, Wv, Wo, Wc, wffb, wqb, wkb, wvb, wob, wcb);
  k_conv <<<NB,   256, 0, stream>>>(x, wffb, bff, outb, psum, psq);
  k_stats<<<256,  256, 0, stream>>>(psum, psq, mean, rstd);
  k_fused<<<NB,   256, SMEM_BYTES, stream>>>(x, f, mask, bq, bk, bv, bo, bc, outb,
                                             wqb, wkb, wvb, wob, wcb, mean, rstd,
                                             (float*)d_out);
}

// Round 2
// 366.326 us; speedup vs baseline: 1.7958x; 1.7958x over previous
//
#include <hip/hip_runtime.h>

#define L_LEN 131072
#define NB    2048     // 64-pos attention blocks
#define NT    1024     // 128-pos GEMM tiles

typedef unsigned short u16;
typedef __attribute__((ext_vector_type(4))) float f32x4;
typedef __attribute__((ext_vector_type(8))) short s16x8;
typedef __attribute__((ext_vector_type(4))) short s16x4;

// ---- ws byte offsets ----
#define WS_OUTT  0ull          // u16[L*256]  conv out, [pos][ch]; becomes hT in-place
#define WS_QT    67108864ull   // u16[L*128]  qT [pos][ch]; reused as rovT by k_attn
#define WS_PSUM  100663296ull  // float[256*1024]
#define WS_PSQ   101711872ull
#define WS_MEAN  102760448ull
#define WS_RSTD  102761472ull
#define WS_WFFB  102762496ull  // short[256*768] (k = t*256+c)
#define WS_WQKB  103155712ull  // short[256*256] rs-folded [Wq;Wk]
#define WS_WVB   103286784ull  // short[128*256]
#define WS_WOB   103352320ull  // short[256*128]
#define WS_WCB   103417856ull  // short[256*256]
#define WS_BQKP  103548928ull  // float[256]
// d_out regions (consumed before k_wc overwrites d_out):
//   v  u16[128*L] at byte 0 ; kT u16[L*128] at byte 33554432

__device__ __forceinline__ u16 f2bf(float v){
  union { float f; unsigned u; } a; a.f = v;
  unsigned r = a.u + 0x7fffu + ((a.u >> 16) & 1u);
  return (u16)(r >> 16);
}
__device__ __forceinline__ float bf2f(u16 u){
  union { unsigned u; float f; } a; a.u = ((unsigned)u) << 16; return a.f;
}
__device__ __forceinline__ f32x4 mfma16(s16x8 a, s16x8 b, f32x4 c){
  return __builtin_amdgcn_mfma_f32_16x16x32_bf16(a, b, c, 0, 0, 0);
}
__device__ __forceinline__ s16x8 ld8(const void* p){ return *(const s16x8*)p; }

// ---------------- K0: weight prep (fp32 -> bf16) ----------------
__global__ __launch_bounds__(256) void k_prep(
    const float* __restrict__ Wff, const float* __restrict__ Wv,
    const float* __restrict__ Wo,  const float* __restrict__ Wc,
    short* __restrict__ wffb, short* __restrict__ wvb,
    short* __restrict__ wob,  short* __restrict__ wcb)
{
  int i = blockIdx.x * 256 + threadIdx.x;
  if (i < 196608){
    int o = i / 768, kk = i % 768;
    int t = kk >> 8, c = kk & 255;
    wffb[i] = (short)f2bf(Wff[(o*256 + c)*3 + t]);
  } else if (i < 229376){ int j = i - 196608; wvb[j] = (short)f2bf(Wv[j]); }
  else if (i < 262144){ int j = i - 229376; wob[j] = (short)f2bf(Wo[j]); }
  else if (i < 327680){ int j = i - 262144; wcb[j] = (short)f2bf(Wc[j]); }
}

// ---------------- K1: dilated conv as GEMM -> outT[pos][ch] + stats ----------------
// tile: 256 och x 128 pos, K=768 (k = t*256+c). 512 threads (8 waves).
__global__ __launch_bounds__(512, 4) void k_conv(
    const float* __restrict__ x, const short* __restrict__ wffb,
    const float* __restrict__ bff, u16* __restrict__ outT,
    float* __restrict__ psum, float* __restrict__ psq)
{
  __shared__ u16 bl[128*40];           // [pos][32ch + pad], row 80B, XOR-swizzled
  const int wg = blockIdx.x, l0 = wg * 128;
  const int tid = threadIdx.x;
  const int w = tid >> 6, lane = tid & 63, p = lane & 15, g = lane >> 4;
  const int cS = tid >> 4, posq = tid & 15;   // staging roles
  f32x4 acc[2][8] = {};
  #pragma unroll 1
  for (int ks = 0; ks < 24; ++ks){
    const int t = ks >> 3, c0 = (ks & 7) * 32;
    {
      const int gbase = l0 + 64*(t-1) + posq*8;
      float vv[8];
      if (gbase >= 0 && gbase <= L_LEN - 8){
        const f32x4* sp = (const f32x4*)(x + (size_t)(c0 + cS)*L_LEN + gbase);
        f32x4 a0 = sp[0], a1 = sp[1];
        vv[0]=a0[0];vv[1]=a0[1];vv[2]=a0[2];vv[3]=a0[3];
        vv[4]=a1[0];vv[5]=a1[1];vv[6]=a1[2];vv[7]=a1[3];
      } else {
        #pragma unroll
        for (int u = 0; u < 8; ++u) vv[u] = 0.f;
      }
      const int col = cS ^ ((posq & 3) << 3);
      #pragma unroll
      for (int u = 0; u < 8; ++u) bl[(posq*8 + u)*40 + col] = f2bf(vv[u]);
    }
    __syncthreads();
    s16x8 af[2];
    af[0] = ld8(wffb + (size_t)(32*w +      p)*768 + ks*32 + 8*g);
    af[1] = ld8(wffb + (size_t)(32*w + 16 + p)*768 + ks*32 + 8*g);
    #pragma unroll
    for (int fn = 0; fn < 8; ++fn){
      const int r = 16*fn + p;
      s16x8 b = ld8(&bl[r*40 + ((8*g) ^ (((r>>3)&3)<<3))]);
      acc[0][fn] = mfma16(af[0], b, acc[0][fn]);
      acc[1][fn] = mfma16(af[1], b, acc[1][fn]);
    }
    __syncthreads();
  }
  // epilogue: bias+relu, store outT (packed), stats
  #pragma unroll
  for (int fm = 0; fm < 2; ++fm){
    const int o0 = 32*w + 16*fm + 4*g;
    float ssum[4] = {0,0,0,0}, ssq[4] = {0,0,0,0};
    #pragma unroll
    for (int fn = 0; fn < 8; ++fn){
      s16x4 pk;
      #pragma unroll
      for (int i = 0; i < 4; ++i){
        float val = fmaxf(acc[fm][fn][i] + bff[o0+i], 0.f);
        pk[i] = (short)f2bf(val);
        ssum[i] += val; ssq[i] += val*val;
      }
      *(s16x4*)(outT + (size_t)(l0 + 16*fn + p)*256 + o0) = pk;
    }
    #pragma unroll
    for (int i = 0; i < 4; ++i){
      float a = ssum[i], b = ssq[i];
      #pragma unroll
      for (int d = 1; d < 16; d <<= 1){ a += __shfl_xor(a, d, 16); b += __shfl_xor(b, d, 16); }
      if (p == 0){ psum[(size_t)(o0+i)*NT + wg] = a; psq[(size_t)(o0+i)*NT + wg] = b; }
    }
  }
}

// ---------------- K2: finalize stats ----------------
__global__ __launch_bounds__(256) void k_stats(
    const float* __restrict__ psum, const float* __restrict__ psq,
    float* __restrict__ mean, float* __restrict__ rstd)
{
  __shared__ float ss[256], sq[256];
  const int ch = blockIdx.x, tid = threadIdx.x;
  float a = 0.f, b = 0.f;
  for (int j = tid; j < NT; j += 256){ a += psum[(size_t)ch*NT + j]; b += psq[(size_t)ch*NT + j]; }
  ss[tid] = a; sq[tid] = b;
  __syncthreads();
  for (int st = 128; st > 0; st >>= 1){
    if (tid < st){ ss[tid] += ss[tid+st]; sq[tid] += sq[tid+st]; }
    __syncthreads();
  }
  if (tid == 0){
    float m = ss[0] / (float)L_LEN;
    float v = sq[0] / (float)L_LEN - m*m;
    mean[ch] = m;
    rstd[ch] = rsqrtf(v + 1e-5f);
  }
}

// ---------------- K3: fold norm into Wq/Wk ----------------
__global__ __launch_bounds__(256) void k_adj(
    const float* __restrict__ Wq, const float* __restrict__ Wk,
    const float* __restrict__ bq, const float* __restrict__ bk,
    const float* __restrict__ mean, const float* __restrict__ rstd,
    short* __restrict__ wqkb, float* __restrict__ bqkp)
{
  __shared__ float red[256];
  const int o = blockIdx.x, c = threadIdx.x;
  const float* src = (o < 128) ? (Wq + (size_t)o*256) : (Wk + (size_t)(o-128)*256);
  const float bias = (o < 128) ? bq[o] : bk[o-128];
  float wv = src[c] * rstd[c];
  wqkb[o*256 + c] = (short)f2bf(wv);
  red[c] = wv * mean[c];
  __syncthreads();
  for (int st = 128; st > 0; st >>= 1){
    if (c < st) red[c] += red[c+st];
    __syncthreads();
  }
  if (c == 0) bqkp[o] = bias - red[0];
}

// ---------------- K4: v = Wv @ f + bv -> v[128][L] ----------------
__global__ __launch_bounds__(256, 4) void k_v(
    const float* __restrict__ fin, const short* __restrict__ wvb,
    const float* __restrict__ bv, u16* __restrict__ vout)
{
  __shared__ u16 bl[128*40];
  const int wg = blockIdx.x, l0 = wg * 128;
  const int tid = threadIdx.x;
  const int w = tid >> 6, lane = tid & 63, p = lane & 15, g = lane >> 4;
  const int posq = tid & 15;
  f32x4 acc[2][8] = {};
  #pragma unroll 1
  for (int ks = 0; ks < 8; ++ks){
    #pragma unroll
    for (int rep = 0; rep < 2; ++rep){
      const int c = rep*16 + (tid >> 4);
      const f32x4* sp = (const f32x4*)(fin + (size_t)(ks*32 + c)*L_LEN + l0 + posq*8);
      f32x4 a0 = sp[0], a1 = sp[1];
      float vv[8] = {a0[0],a0[1],a0[2],a0[3],a1[0],a1[1],a1[2],a1[3]};
      const int col = c ^ ((posq & 3) << 3);
      #pragma unroll
      for (int u = 0; u < 8; ++u) bl[(posq*8 + u)*40 + col] = f2bf(vv[u]);
    }
    __syncthreads();
    s16x8 af[2];
    af[0] = ld8(wvb + (size_t)(32*w +      p)*256 + ks*32 + 8*g);
    af[1] = ld8(wvb + (size_t)(32*w + 16 + p)*256 + ks*32 + 8*g);
    #pragma unroll
    for (int fn = 0; fn < 8; ++fn){
      const int r = 16*fn + p;
      s16x8 b = ld8(&bl[r*40 + ((8*g) ^ (((r>>3)&3)<<3))]);
      acc[0][fn] = mfma16(af[0], b, acc[0][fn]);
      acc[1][fn] = mfma16(af[1], b, acc[1][fn]);
    }
    __syncthreads();
  }
  #pragma unroll
  for (int fm = 0; fm < 2; ++fm){
    #pragma unroll
    for (int fn = 0; fn < 8; ++fn){
      #pragma unroll
      for (int i = 0; i < 4; ++i){
        const int cv = 32*w + 16*fm + 4*g + i;
        vout[(size_t)cv*L_LEN + l0 + 16*fn + p] = f2bf(acc[fm][fn][i] + bv[cv]);
      }
    }
  }
}

// ---------------- K5: [q;k] = Wqk' @ out + bqk' -> qT, kT ----------------
__global__ __launch_bounds__(512, 4) void k_qk(
    const u16* __restrict__ outT, const short* __restrict__ wqkb,
    const float* __restrict__ bqkp, u16* __restrict__ qT, u16* __restrict__ kT)
{
  extern __shared__ u16 tile[];        // [128 pos][256 ch] swizzled, 64KB
  const int wg = blockIdx.x, l0 = wg * 128;
  const int tid = threadIdx.x;
  const int w = tid >> 6, lane = tid & 63, p = lane & 15, g = lane >> 4;
  #pragma unroll
  for (int rep = 0; rep < 8; ++rep){
    const int idx = rep*512 + tid;
    const int r = idx >> 5, cc = idx & 31;
    s16x8 vput = ld8(outT + (size_t)(l0 + r)*256 + cc*8);
    *(s16x8*)(&tile[r*256 + ((cc*8) ^ ((r&7)<<3))]) = vput;
  }
  __syncthreads();
  f32x4 acc[2][8] = {};
  #pragma unroll
  for (int kk = 0; kk < 8; ++kk){
    s16x8 af[2];
    af[0] = ld8(wqkb + (size_t)(32*w +      p)*256 + 32*kk + 8*g);
    af[1] = ld8(wqkb + (size_t)(32*w + 16 + p)*256 + 32*kk + 8*g);
    #pragma unroll
    for (int fn = 0; fn < 8; ++fn){
      const int r = 16*fn + p;
      s16x8 b = ld8(&tile[r*256 + ((32*kk + 8*g) ^ ((r&7)<<3))]);
      acc[0][fn] = mfma16(af[0], b, acc[0][fn]);
      acc[1][fn] = mfma16(af[1], b, acc[1][fn]);
    }
  }
  #pragma unroll
  for (int fm = 0; fm < 2; ++fm){
    const int R0 = 32*w + 16*fm + 4*g;
    #pragma unroll
    for (int fn = 0; fn < 8; ++fn){
      s16x4 pk;
      #pragma unroll
      for (int i = 0; i < 4; ++i) pk[i] = (short)f2bf(acc[fm][fn][i] + bqkp[R0+i]);
      const size_t row = (size_t)(l0 + 16*fn + p);
      if (R0 < 128) *(s16x4*)(qT + row*128 + R0)       = pk;
      else          *(s16x4*)(kT + row*128 + R0 - 128) = pk;
    }
  }
}

// ---------------- K6: attention per 64-block + Wo; h in-place over outT ----------------
__global__ __launch_bounds__(256, 4) void k_attn(
    const u16* __restrict__ qT, const u16* __restrict__ kT,
    const u16* __restrict__ vg, const short* __restrict__ wob,
    const float* __restrict__ bo, const float* __restrict__ mask,
    u16* __restrict__ outT, u16* __restrict__ rovg /*unused store target = qT region*/)
{
  __shared__ u16 klds[16384];          // 32KB: k-window; overlays: p [0,8K), rov [8K,16K) (u16 idx)
  __shared__ float maskw[128];
  const int tid = threadIdx.x;
  const int w = tid >> 6, lane = tid & 63, p = lane & 15, g = lane >> 4;
  const int n = blockIdx.x, s = n * 64;
  const float SCALE = 0.08838834764831845f;

  #pragma unroll
  for (int rep = 0; rep < 8; ++rep){
    const int idx = rep*256 + tid;
    const int m = idx >> 4, cc = idx & 15;
    const int gpos = s - 32 + m;
    s16x8 vput = {};
    if (gpos >= 0 && gpos < L_LEN) vput = ld8(kT + (size_t)gpos*128 + cc*8);
    *(s16x8*)(&klds[m*128 + ((cc*8) ^ ((m&7)<<3))]) = vput;
  }
  if (tid < 128){
    const int gp = s - 32 + tid;
    maskw[tid] = (gp >= 0 && gp < L_LEN) ? mask[gp] : 0.f;
  }
  __syncthreads();

  // energy: D[l][m], wave w owns l in [16w,16w+16)
  f32x4 e[8] = {};
  #pragma unroll
  for (int kk = 0; kk < 4; ++kk){
    s16x8 aq = ld8(qT + (size_t)(s + 16*w + p)*128 + 32*kk + 8*g);
    #pragma unroll
    for (int fn = 0; fn < 8; ++fn){
      const int m = 16*fn + p;
      s16x8 b = ld8(&klds[m*128 + ((32*kk + 8*g) ^ ((m&7)<<3))]);
      e[fn] = mfma16(aq, b, e[fn]);
    }
  }
  // softmax (z stored back into e)
  float M[4] = {-1e30f,-1e30f,-1e30f,-1e30f};
  float S[4] = {0.f,0.f,0.f,0.f};
  #pragma unroll
  for (int fn = 0; fn < 8; ++fn){
    #pragma unroll
    for (int i = 0; i < 4; ++i){
      const int mm = 16*fn + p;
      const int l_ = 16*w + 4*g + i;
      const int d = mm - l_;
      const float fmv = (d >= 0 && d < 64) ? maskw[mm] : 0.f;
      const float z = e[fn][i]*SCALE + __logf(fmv + 1e-6f);
      e[fn][i] = z;
      M[i] = fmaxf(M[i], z);
    }
  }
  #pragma unroll
  for (int i = 0; i < 4; ++i){
    #pragma unroll
    for (int d = 1; d < 16; d <<= 1) M[i] = fmaxf(M[i], __shfl_xor(M[i], d, 16));
  }
  #pragma unroll
  for (int fn = 0; fn < 8; ++fn){
    #pragma unroll
    for (int i = 0; i < 4; ++i){
      const float pv = __expf(e[fn][i] - M[i]);
      e[fn][i] = pv;
      S[i] += pv;
    }
  }
  #pragma unroll
  for (int i = 0; i < 4; ++i){
    #pragma unroll
    for (int d = 1; d < 16; d <<= 1) S[i] += __shfl_xor(S[i], d, 16);
  }
  float rinv[4];
  #pragma unroll
  for (int i = 0; i < 4; ++i) rinv[i] = 1.f / S[i];
  __syncthreads();   // all waves done reading klds
  #pragma unroll
  for (int fn = 0; fn < 8; ++fn){
    #pragma unroll
    for (int i = 0; i < 4; ++i){
      const int mm = 16*fn + p;
      const int l_ = 16*w + 4*g + i;
      const int d = mm - l_;
      const float fmv = (d >= 0 && d < 64) ? maskw[mm] : 0.f;
      klds[l_*128 + (mm ^ ((l_&7)<<3))] = f2bf(e[fn][i] * rinv[i] * fmv);
    }
  }
  __syncthreads();

  // PV: D[cv][l]; A = v from global (clamped), B = p in LDS
  f32x4 accp[2][4] = {};
  #pragma unroll
  for (int kk = 0; kk < 4; ++kk){
    int gp0 = s - 32 + 32*kk + 8*g;
    gp0 = max(0, min(gp0, L_LEN - 8));
    s16x8 a0 = ld8(vg + (size_t)(32*w +      p)*L_LEN + gp0);
    s16x8 a1 = ld8(vg + (size_t)(32*w + 16 + p)*L_LEN + gp0);
    #pragma unroll
    for (int fn = 0; fn < 4; ++fn){
      const int l_ = 16*fn + p;
      s16x8 b = ld8(&klds[l_*128 + ((32*kk + 8*g) ^ ((l_&7)<<3))]);
      accp[0][fn] = mfma16(a0, b, accp[0][fn]);
      accp[1][fn] = mfma16(a1, b, accp[1][fn]);
    }
  }
  #pragma unroll
  for (int fm = 0; fm < 2; ++fm){
    #pragma unroll
    for (int fn = 0; fn < 4; ++fn){
      const int l_ = 16*fn + p;
      s16x4 pk;
      #pragma unroll
      for (int i = 0; i < 4; ++i) pk[i] = (short)f2bf(fmaxf(accp[fm][fn][i], 0.f));
      const int cv0 = 32*w + 16*fm + 4*g;
      *(s16x4*)(&klds[8192 + l_*128 + (cv0 ^ ((l_&7)<<3))]) = pk;
    }
  }
  __syncthreads();

  // Wo: D[och][l]; A = wob global, B = rov LDS; epilogue h = oo*pm + out (in-place)
  f32x4 acco[4][4] = {};
  #pragma unroll
  for (int kk = 0; kk < 4; ++kk){
    s16x8 a[4];
    #pragma unroll
    for (int fm = 0; fm < 4; ++fm)
      a[fm] = ld8(wob + (size_t)(64*w + 16*fm + p)*128 + 32*kk + 8*g);
    #pragma unroll
    for (int fn = 0; fn < 4; ++fn){
      const int l_ = 16*fn + p;
      s16x8 b = ld8(&klds[8192 + l_*128 + ((32*kk + 8*g) ^ ((l_&7)<<3))]);
      #pragma unroll
      for (int fm = 0; fm < 4; ++fm) acco[fm][fn] = mfma16(a[fm], b, acco[fm][fn]);
    }
  }
  #pragma unroll
  for (int fm = 0; fm < 4; ++fm){
    const int o0 = 64*w + 16*fm + 4*g;
    #pragma unroll
    for (int fn = 0; fn < 4; ++fn){
      const int l_ = 16*fn + p;
      const float pml = maskw[32 + l_];
      u16* hp = outT + (size_t)(s + l_)*256 + o0;
      s16x4 res = *(const s16x4*)hp;
      s16x4 pk;
      #pragma unroll
      for (int i = 0; i < 4; ++i){
        float hv = (acco[fm][fn][i] + bo[o0+i]) * pml + bf2f((u16)res[i]);
        pk[i] = (short)f2bf(hv);
      }
      *(s16x4*)hp = pk;
    }
  }
  (void)rovg;
}

// ---------------- K7: y = Wc @ h + bc; dout = (x + y) * mask ----------------
__global__ __launch_bounds__(512, 4) void k_wc(
    const u16* __restrict__ hT, const short* __restrict__ wcb,
    const float* __restrict__ bc, const float* __restrict__ x,
    const float* __restrict__ mask, float* __restrict__ dout)
{
  extern __shared__ u16 tile[];
  const int wg = blockIdx.x, l0 = wg * 128;
  const int tid = threadIdx.x;
  const int w = tid >> 6, lane = tid & 63, p = lane & 15, g = lane >> 4;
  #pragma unroll
  for (int rep = 0; rep < 8; ++rep){
    const int idx = rep*512 + tid;
    const int r = idx >> 5, cc = idx & 31;
    s16x8 vput = ld8(hT + (size_t)(l0 + r)*256 + cc*8);
    *(s16x8*)(&tile[r*256 + ((cc*8) ^ ((r&7)<<3))]) = vput;
  }
  __syncthreads();
  f32x4 acc[2][8] = {};
  #pragma unroll
  for (int kk = 0; kk < 8; ++kk){
    s16x8 af[2];
    af[0] = ld8(wcb + (size_t)(32*w +      p)*256 + 32*kk + 8*g);
    af[1] = ld8(wcb + (size_t)(32*w + 16 + p)*256 + 32*kk + 8*g);
    #pragma unroll
    for (int fn = 0; fn < 8; ++fn){
      const int r = 16*fn + p;
      s16x8 b = ld8(&tile[r*256 + ((32*kk + 8*g) ^ ((r&7)<<3))]);
      acc[0][fn] = mfma16(af[0], b, acc[0][fn]);
      acc[1][fn] = mfma16(af[1], b, acc[1][fn]);
    }
  }
  #pragma unroll
  for (int fm = 0; fm < 2; ++fm){
    const int o0 = 32*w + 16*fm + 4*g;
    #pragma unroll
    for (int fn = 0; fn < 8; ++fn){
      const int pos = l0 + 16*fn + p;
      const float mk = mask[pos];
      #pragma unroll
      for (int i = 0; i < 4; ++i){
        const size_t idx = (size_t)(o0+i)*L_LEN + pos;
        dout[idx] = (x[idx] + acc[fm][fn][i] + bc[o0+i]) * mk;
      }
    }
  }
}

extern "C" void kernel_launch(void* const* d_in, const int* in_sizes, int n_in,
                              void* d_out, int out_size, void* d_ws, size_t ws_size,
                              hipStream_t stream)
{
  (void)in_sizes; (void)n_in; (void)out_size; (void)ws_size;
  const float* x    = (const float*)d_in[0];
  const float* f    = (const float*)d_in[1];
  const float* mask = (const float*)d_in[2];
  const float* Wff  = (const float*)d_in[3];
  const float* bff  = (const float*)d_in[4];
  const float* Wq   = (const float*)d_in[5];
  const float* bq   = (const float*)d_in[6];
  const float* Wk   = (const float*)d_in[7];
  const float* bk   = (const float*)d_in[8];
  const float* Wv   = (const float*)d_in[9];
  const float* bv   = (const float*)d_in[10];
  const float* Wo   = (const float*)d_in[11];
  const float* bo   = (const float*)d_in[12];
  const float* Wc   = (const float*)d_in[13];
  const float* bc   = (const float*)d_in[14];

  char* ws = (char*)d_ws;
  u16*   outT = (u16*)(ws + WS_OUTT);
  u16*   qT   = (u16*)(ws + WS_QT);
  float* psum = (float*)(ws + WS_PSUM);
  float* psq  = (float*)(ws + WS_PSQ);
  float* mean = (float*)(ws + WS_MEAN);
  float* rstd = (float*)(ws + WS_RSTD);
  short* wffb = (short*)(ws + WS_WFFB);
  short* wqkb = (short*)(ws + WS_WQKB);
  short* wvb  = (short*)(ws + WS_WVB);
  short* wob  = (short*)(ws + WS_WOB);
  short* wcb  = (short*)(ws + WS_WCB);
  float* bqkp = (float*)(ws + WS_BQKP);

  u16* vbuf = (u16*)d_out;                       // v[128][L]
  u16* ktb  = (u16*)((char*)d_out + 33554432);   // kT[L][128]

  (void)hipFuncSetAttribute((const void*)k_qk,
                            hipFuncAttributeMaxDynamicSharedMemorySize, 65536);
  (void)hipFuncSetAttribute((const void*)k_wc,
                            hipFuncAttributeMaxDynamicSharedMemorySize, 65536);

  k_prep <<<1280, 256, 0, stream>>>(Wff, Wv, Wo, Wc, wffb, wvb, wob, wcb);
  k_conv <<<NT,   512, 0, stream>>>(x, wffb, bff, outT, psum, psq);
  k_stats<<<256,  256, 0, stream>>>(psum, psq, mean, rstd);
  k_adj  <<<256,  256, 0, stream>>>(Wq, Wk, bq, bk, mean, rstd, wqkb, bqkp);
  k_v    <<<NT,   256, 0, stream>>>(f, wvb, bv, vbuf);
  k_qk   <<<NT,   512, 65536, stream>>>(outT, wqkb, bqkp, qT, ktb);
  k_attn <<<NB,   256, 0, stream>>>(qT, ktb, vbuf, wob, bo, mask, outT, qT);
  k_wc   <<<NT,   512, 65536, stream>>>(outT, wcb, bc, x, mask, (float*)d_out);
}